// Round 2
// baseline (305.583 us; speedup 1.0000x reference)
//
#include <hip/hip_runtime.h>

// GraphAttention fused forward for MI355X (gfx950).
// v3: attn block = (b, 32-row i-tile, j-quarter of 512); 4 waves split 2x2:
// wave = (16-row rowset, 64-col j-half) x ALL 4 heads -> each staged adj/msk
// element read once per block (4x amortization vs v1) at v1-like occupancy
// (4 blocks/CU, VGPR<=128 via launch_bounds(256,4), LDS 36.9KB).
// Staging: global_load_lds width 16, XOR-swizzled source, conflict-free
// ds_read_b128. Cross-(j-half) merge in LDS, partials to part/lpart,
// v1's final_kernel does softmax /l + bias + BN + ReLU + transpose + out.
// B=4, N=2048, F=64, FP=32, H=4.  Output: [B,N,H*FP] f32 ++ uloss ++ eloss.

#define B_ 4
#define N_ 2048
#define F_ 64
#define FP_ 32
#define H_ 4
#define C_ 128
#define IT_ 32                 // i-rows per attn block (2 rowsets of 16)
#define ITILES_ (N_ / IT_)     // 64
#define JCA_ 4                 // j-chunks -> grid 1024 (4 blocks/CU)
#define JSPANA_ (N_ / JCA_)    // 512
#define JST_ 128               // j per LDS stage
#define NST_ (JSPANA_ / JST_)  // 4 stages

typedef __attribute__((ext_vector_type(8))) short short8v;   // 8 bf16 = 4 VGPRs
typedef __attribute__((ext_vector_type(4))) float f32x4;     // MFMA C/D
typedef __attribute__((ext_vector_type(4))) int   int4v;

union PkU { int4v i; short8v s; };

__device__ __forceinline__ unsigned short f2bf(float f) {    // RNE fp32->bf16
    unsigned u = __float_as_uint(f);
    u += 0x7fffu + ((u >> 16) & 1u);
    return (unsigned short)(u >> 16);
}

// 8 elementwise attn values -> l,A accumulate + packed bf16 A-frag dword x4.
__device__ __forceinline__ void attn_qstep(
    float si, const float* av, const float* mv, const float* tv,
    float& l, float& A, int4v& apk)
{
#pragma unroll
    for (int qq = 0; qq < 4; ++qq) {
        float d0 = si + tv[2 * qq];
        d0 = fmaxf(d0, 0.2f * d0) + mv[2 * qq];       // LeakyReLU(0.2) + mask
        float e0 = __expf(d0);                        // bounded: no max-subtract
        float p0 = e0 * av[2 * qq];
        float d1 = si + tv[2 * qq + 1];
        d1 = fmaxf(d1, 0.2f * d1) + mv[2 * qq + 1];
        float e1 = __expf(d1);
        float p1 = e1 * av[2 * qq + 1];
        l += e0 + e1;
        A += p0 + p1;
        unsigned u0 = __float_as_uint(p0) + 0x8000u;  // round-half-up, p>=0
        unsigned u1 = __float_as_uint(p1) + 0x8000u;
        apk[qq] = (int)__builtin_amdgcn_perm(u1, u0, 0x07060302u); // [p1.hi|p0.hi]
    }
}

// async global->LDS, 16 B per lane; LDS dest wave-uniform base + lane*16.
__device__ __forceinline__ void gl_lds16(const float* g, float* l) {
    __builtin_amdgcn_global_load_lds(
        (const __attribute__((address_space(1))) unsigned*)g,
        (__attribute__((address_space(3))) unsigned*)l, 16, 0, 0);
}

// ---------------------------------------------------------------- kernel 1
// feats = x@W per head via MFMA; writes featsT bf16 [b][h][d][n] + s,t fp32.
__global__ __launch_bounds__(256) void prep_kernel(
    const float* __restrict__ x, const float* __restrict__ W,
    const float* __restrict__ a_self, const float* __restrict__ a_neigh,
    unsigned short* __restrict__ featsT, float* __restrict__ sbuf,
    float* __restrict__ tbuf)
{
    int blk = blockIdx.x;              // b*32 + nt
    int b = blk >> 5, nt = blk & 31;
    int n0 = nt << 6;
    int t = threadIdx.x, h = t >> 6, lane = t & 63;
    int quad = lane >> 4, col = lane & 15;

    short8v bw[2][2];
    const float* Wh = W + (size_t)h * F_ * FP_;
#pragma unroll
    for (int kc = 0; kc < 2; ++kc)
#pragma unroll
        for (int dt = 0; dt < 2; ++dt)
#pragma unroll
            for (int e = 0; e < 8; ++e) {
                int f = kc * 32 + quad * 8 + e;
                bw[kc][dt][e] = (short)f2bf(Wh[f * FP_ + dt * 16 + col]);
            }
    float as0 = a_self[h * FP_ + col],  as1 = a_self[h * FP_ + 16 + col];
    float an0 = a_neigh[h * FP_ + col], an1 = a_neigh[h * FP_ + 16 + col];
    size_t hrow = ((size_t)b * H_ + h) * N_;
    size_t ftb  = ((size_t)b * H_ + h) * FP_;

    for (int ms = 0; ms < 4; ++ms) {
        int row = n0 + ms * 16 + col;          // A row m = lane&15
        const float* xr = x + ((size_t)b * N_ + row) * F_;
        f32x4 acc0 = {0.f, 0.f, 0.f, 0.f}, acc1 = {0.f, 0.f, 0.f, 0.f};
#pragma unroll
        for (int kc = 0; kc < 2; ++kc) {
            float4 x0 = *(const float4*)(xr + kc * 32 + quad * 8);
            float4 x1 = *(const float4*)(xr + kc * 32 + quad * 8 + 4);
            short8v av;
            av[0] = (short)f2bf(x0.x); av[1] = (short)f2bf(x0.y);
            av[2] = (short)f2bf(x0.z); av[3] = (short)f2bf(x0.w);
            av[4] = (short)f2bf(x1.x); av[5] = (short)f2bf(x1.y);
            av[6] = (short)f2bf(x1.z); av[7] = (short)f2bf(x1.w);
            acc0 = __builtin_amdgcn_mfma_f32_16x16x32_bf16(av, bw[kc][0], acc0, 0, 0, 0);
            acc1 = __builtin_amdgcn_mfma_f32_16x16x32_bf16(av, bw[kc][1], acc1, 0, 0, 0);
        }
        {   // C layout: row = quad*4+rr, col = lane&15 (verified m89/m91)
            ushort4 v0, v1;
            v0.x = f2bf(acc0[0]); v0.y = f2bf(acc0[1]);
            v0.z = f2bf(acc0[2]); v0.w = f2bf(acc0[3]);
            v1.x = f2bf(acc1[0]); v1.y = f2bf(acc1[1]);
            v1.z = f2bf(acc1[2]); v1.w = f2bf(acc1[3]);
            size_t nidx = (size_t)n0 + ms * 16 + quad * 4;
            *(ushort4*)(featsT + (ftb + col) * N_ + nidx)      = v0;
            *(ushort4*)(featsT + (ftb + 16 + col) * N_ + nidx) = v1;
        }
#pragma unroll
        for (int rr = 0; rr < 4; ++rr) {
            float sv = acc0[rr] * as0 + acc1[rr] * as1;
            float tv = acc0[rr] * an0 + acc1[rr] * an1;
#pragma unroll
            for (int off = 8; off; off >>= 1) {
                sv += __shfl_down(sv, off);
                tv += __shfl_down(tv, off);
            }
            if (col == 0) {
                int n = n0 + ms * 16 + quad * 4 + rr;
                sbuf[hrow + n] = sv;
                tbuf[hrow + n] = tv;
            }
        }
    }
}

// ---------------------------------------------------------------- kernel 2
// Block = (b, it, jc). 4 waves: wave w -> rowset rs=w>>1 (16 rows),
// j-half jh=w&1 (64 cols), ALL 4 heads. Staged adj/msk read ONCE per block.
__global__ __launch_bounds__(256, 4) void attn_kernel(
    const float* __restrict__ adj, const float* __restrict__ msk,
    const unsigned short* __restrict__ featsT,
    const float* __restrict__ sbuf, const float* __restrict__ tbuf,
    float* __restrict__ part, float* __restrict__ lpart)
{
    __shared__ __align__(16) float ladj[IT_ * JST_];   // 16 KB (merge reuse)
    __shared__ __align__(16) float lmsk[IT_ * JST_];   // 16 KB
    __shared__ __align__(16) float lt[H_ * JST_];      //  2 KB
    __shared__ float lmrg[512];                        //  2 KB l/A merge

    const int blk = blockIdx.x;
    const int jc = blk & (JCA_ - 1);
    const int it = (blk >> 2) & (ITILES_ - 1);
    const int b  = blk >> 8;
    const int t = threadIdx.x, w = t >> 6, lane = t & 63;
    const int quad = lane >> 4, r = lane & 15;
    const int rs = w >> 1, jh = w & 1;
    const int i0 = it * IT_;
    const int jbase = jc * JSPANA_;
    const int rowl = rs * 16 + r;                      // lane's P/adj row

    float si[H_];
#pragma unroll
    for (int hh = 0; hh < H_; ++hh)
        si[hh] = sbuf[((size_t)b * H_ + hh) * N_ + i0 + rowl];

    // featsT base: head 0, d=r, col jbase (B-frag: lane(quad,r) = featsT[r][j+quad*8+e])
    const unsigned short* fb = featsT + ((size_t)b * H_ * FP_ + r) * N_ + jbase;

    // staging: wave stages adj/msk rows 8w..8w+7; instr ii covers rows 8w+2ii,+1.
    // lane: row += (lane>>5), slot sl=lane&31; source col = (sl ^ (row&7))*4
    // (inverse-swizzled source, linear LDS dest -> swizzled read below).
    const int sl = lane & 31;
    const float* asrc[4];
    const float* msrc[4];
#pragma unroll
    for (int ii = 0; ii < 4; ++ii) {
        int row = 8 * w + 2 * ii + (lane >> 5);
        int cs = (sl ^ (row & 7)) << 2;
        size_t go = ((size_t)b * N_ + i0 + row) * N_ + jbase + cs;
        asrc[ii] = adj + go;
        msrc[ii] = msk + go;
    }
    // t staging: wave 0 -> heads 0,1; wave 1 -> heads 2,3 (linear, broadcast-read)
    const float* tsrc = tbuf + ((size_t)b * H_ + (2 * (w & 1) + (lane >> 5))) * N_
                        + jbase + sl * 4;

    f32x4 acc[H_][2];
#pragma unroll
    for (int hh = 0; hh < H_; ++hh) {
        acc[hh][0] = (f32x4){0.f, 0.f, 0.f, 0.f};
        acc[hh][1] = (f32x4){0.f, 0.f, 0.f, 0.f};
    }
    float lA[H_] = {0.f, 0.f, 0.f, 0.f}, AA[H_] = {0.f, 0.f, 0.f, 0.f};

    for (int st = 0; st < NST_; ++st) {
        const int j0 = st * JST_;
        __syncthreads();                       // prev compute done
#pragma unroll
        for (int ii = 0; ii < 4; ++ii) {
            gl_lds16(asrc[ii] + j0, ladj + (8 * w + 2 * ii) * JST_);
            gl_lds16(msrc[ii] + j0, lmsk + (8 * w + 2 * ii) * JST_);
        }
        if (w < 2) gl_lds16(tsrc + j0, lt + w * 256);
        __syncthreads();                       // vmcnt drained -> stage ready
#pragma unroll
        for (int kc = 0; kc < 2; ++kc) {
            const int jt = jh * 64 + kc * 32 + quad * 8;   // col in stage
            const int s0 = ((jt >> 2) ^ (r & 7)) << 2;     // swizzled slots
            const int s1 = (((jt >> 2) + 1) ^ (r & 7)) << 2;
            float4 a0 = *(const float4*)&ladj[rowl * JST_ + s0];
            float4 a1 = *(const float4*)&ladj[rowl * JST_ + s1];
            float4 m0 = *(const float4*)&lmsk[rowl * JST_ + s0];
            float4 m1 = *(const float4*)&lmsk[rowl * JST_ + s1];
            float av[8] = {a0.x, a0.y, a0.z, a0.w, a1.x, a1.y, a1.z, a1.w};
            float mv[8] = {m0.x, m0.y, m0.z, m0.w, m1.x, m1.y, m1.z, m1.w};
            const unsigned short* fjb = fb + j0 + jt;
#pragma unroll
            for (int hh = 0; hh < H_; ++hh) {  // adj/msk reused 4x in regs
                float4 t0 = *(const float4*)&lt[hh * JST_ + jt];      // bcast
                float4 t1 = *(const float4*)&lt[hh * JST_ + jt + 4];
                float tv[8] = {t0.x, t0.y, t0.z, t0.w, t1.x, t1.y, t1.z, t1.w};
                PkU ap;
                attn_qstep(si[hh], av, mv, tv, lA[hh], AA[hh], ap.i);
                const unsigned short* fh = fjb + (size_t)hh * FP_ * N_;
                short8v bv0 = *(const short8v*)fh;                    // L2/L3
                short8v bv1 = *(const short8v*)(fh + (size_t)16 * N_);
                acc[hh][0] = __builtin_amdgcn_mfma_f32_16x16x32_bf16(ap.s, bv0, acc[hh][0], 0, 0, 0);
                acc[hh][1] = __builtin_amdgcn_mfma_f32_16x16x32_bf16(ap.s, bv1, acc[hh][1], 0, 0, 0);
            }
        }
    }
    // fold quad groups -> per-row totals in lanes 0-15 (rows rs*16..+15, j-half jh)
#pragma unroll
    for (int hh = 0; hh < H_; ++hh) {
        lA[hh] += __shfl_down(lA[hh], 32); lA[hh] += __shfl_down(lA[hh], 16);
        AA[hh] += __shfl_down(AA[hh], 32); AA[hh] += __shfl_down(AA[hh], 16);
    }

    // merge j-halves: jh1 waves publish, jh0 waves sum + write partials
    __syncthreads();                           // staging LDS free for reuse
    if (jh == 1) {
#pragma unroll
        for (int hh = 0; hh < H_; ++hh) {
            *(f32x4*)&ladj[rs * 2048 + (hh * 2 + 0) * 256 + lane * 4] = acc[hh][0];
            *(f32x4*)&ladj[rs * 2048 + (hh * 2 + 1) * 256 + lane * 4] = acc[hh][1];
        }
        if (lane < 16)
#pragma unroll
            for (int hh = 0; hh < H_; ++hh) {
                lmrg[rs * 256 + hh * 32 + lane]      = lA[hh];
                lmrg[rs * 256 + hh * 32 + 16 + lane] = AA[hh];
            }
    }
    __syncthreads();
    if (jh == 0) {
#pragma unroll
        for (int hh = 0; hh < H_; ++hh) {
            size_t pb = (((size_t)(b * H_ + hh) * ITILES_ + it) * JCA_ + jc) * 1024;
#pragma unroll
            for (int dt = 0; dt < 2; ++dt) {
                f32x4 c = acc[hh][dt]
                        + *(const f32x4*)&ladj[rs * 2048 + (hh * 2 + dt) * 256 + lane * 4];
                *(f32x4*)&part[pb + (rs * 2 + dt) * 256 + lane * 4] = c;
            }
            if (lane < 16) {
                size_t lb = (((size_t)(b * H_ + hh) * ITILES_ + it) * JCA_ + jc) * 64;
                lpart[lb + rs * 16 + lane]      = lA[hh] + lmrg[rs * 256 + hh * 32 + lane];
                lpart[lb + 32 + rs * 16 + lane] = AA[hh] + lmrg[rs * 256 + hh * 32 + 16 + lane];
            }
        }
    }
}

// ---------------------------------------------------------------- kernel 3
// Block = (b, 32-row i-tile). Merge jc partials, /l, bias, BN, ReLU,
// LDS transpose, coalesced out; per-(block,h) eloss partial.
__global__ __launch_bounds__(256) void final_kernel(
    const float* __restrict__ part, const float* __restrict__ lpart,
    const float* __restrict__ bias, const float* __restrict__ gamma,
    const float* __restrict__ beta, const float* __restrict__ mmean,
    const float* __restrict__ mvar, float* __restrict__ lossbuf,
    float* __restrict__ out)
{
    __shared__ float ldsl[H_ * IT_];
    __shared__ float ldso[IT_ * 132];
    int blk = blockIdx.x;              // b*64 + it
    int b = blk >> 6, it = blk & 63;
    int t = threadIdx.x, h = t >> 6, lane = t & 63;
    int quad = lane >> 4, col = lane & 15;

    size_t pb = (((size_t)(b * H_ + h) * ITILES_ + it) * JCA_) * 1024;
    f32x4 C[4];
#pragma unroll
    for (int k = 0; k < 4; ++k) C[k] = (f32x4){0.f, 0.f, 0.f, 0.f};
#pragma unroll
    for (int c = 0; c < JCA_; ++c)
#pragma unroll
        for (int k = 0; k < 4; ++k)
            C[k] += *(const f32x4*)&part[pb + c * 1024 + k * 256 + lane * 4];

    size_t lb = (((size_t)(b * H_ + h) * ITILES_ + it) * JCA_) * 64;
    if (lane < 32) {
        float lt = 0.f, At = 0.f;
#pragma unroll
        for (int c = 0; c < JCA_; ++c) {
            lt += lpart[lb + c * 64 + lane];
            At += lpart[lb + c * 64 + 32 + lane];
        }
        ldsl[h * IT_ + lane] = lt;
        float e = At / lt;
#pragma unroll
        for (int off = 16; off; off >>= 1) e += __shfl_down(e, off);
        if (lane == 0) lossbuf[blk * H_ + h] = e;
    }
    __syncthreads();
#pragma unroll
    for (int dt = 0; dt < 2; ++dt) {
        int c = h * FP_ + dt * 16 + col;
        float sc = rsqrtf(mvar[c] + 1e-3f) * gamma[c];
        float sh = beta[c] - mmean[c] * sc;
        float bi = bias[c];
#pragma unroll
        for (int rr = 0; rr < 2; ++rr) {
            f32x4 Cv = C[rr * 2 + dt];
#pragma unroll
            for (int rrr = 0; rrr < 4; ++rrr) {
                int row = rr * 16 + quad * 4 + rrr;
                float node = Cv[rrr] / ldsl[h * IT_ + row] + bi;
                float o = node * sc + sh;
                ldso[row * 132 + c] = o > 0.f ? o : 0.f;
            }
        }
    }
    __syncthreads();
#pragma unroll
    for (int ps = 0; ps < 4; ++ps) {
        int s = ps * 256 + t;
        int row = s >> 5, c4 = (s & 31) * 4;
        *(float4*)(out + ((size_t)b * N_ + it * IT_ + row) * C_ + c4) =
            *(const float4*)&ldso[row * 132 + c4];
    }
}

// ---------------------------------------------------------------- kernel 4
__global__ __launch_bounds__(256) void loss_kernel(
    const float* __restrict__ lossbuf, float* __restrict__ out)
{
    float e = 0.f;
    for (int idx = threadIdx.x; idx < B_ * ITILES_ * H_; idx += 256)
        e += lossbuf[idx];
    __shared__ float se[256];
    se[threadIdx.x] = e;
    __syncthreads();
    for (int o = 128; o; o >>= 1) {
        if (threadIdx.x < o) se[threadIdx.x] += se[threadIdx.x + o];
        __syncthreads();
    }
    if (threadIdx.x == 0) {
        out[(size_t)B_ * N_ * C_]     = 0.f;                 // uloss == 0 exactly
        out[(size_t)B_ * N_ * C_ + 1] = se[0] * (1.f / N_);  // eloss
    }
}

// ---------------------------------------------------------------- launch
extern "C" void kernel_launch(void* const* d_in, const int* in_sizes, int n_in,
                              void* d_out, int out_size, void* d_ws, size_t ws_size,
                              hipStream_t stream)
{
    const float* x         = (const float*)d_in[0];
    const float* adj       = (const float*)d_in[1];
    const float* attn_mask = (const float*)d_in[2];
    const float* W         = (const float*)d_in[3];
    const float* a_self    = (const float*)d_in[4];
    const float* a_neigh   = (const float*)d_in[5];
    const float* bias      = (const float*)d_in[6];
    const float* gamma     = (const float*)d_in[7];
    const float* beta      = (const float*)d_in[8];
    const float* mmean     = (const float*)d_in[9];
    const float* mvar      = (const float*)d_in[10];
    float* out = (float*)d_out;

    float* ws = (float*)d_ws;
    unsigned short* featsT = (unsigned short*)ws;                      // 1,048,576 u16
    float* sbuf  = ws + 524288;                                        //    32,768 f
    float* tbuf  = sbuf + (size_t)B_ * H_ * N_;                        //    32,768 f
    float* part  = tbuf + (size_t)B_ * H_ * N_;                        // 4,194,304 f
    float* lpart = part + (size_t)B_ * H_ * ITILES_ * JCA_ * 1024;     //   262,144 f
    float* lossb = lpart + (size_t)B_ * H_ * ITILES_ * JCA_ * 64;      //     1,024 f

    hipLaunchKernelGGL(prep_kernel, dim3(B_ * 32), dim3(256), 0, stream,
                       x, W, a_self, a_neigh, featsT, sbuf, tbuf);
    hipLaunchKernelGGL(attn_kernel, dim3(B_ * ITILES_ * JCA_), dim3(256), 0, stream,
                       adj, attn_mask, featsT, sbuf, tbuf, part, lpart);
    hipLaunchKernelGGL(final_kernel, dim3(B_ * ITILES_), dim3(256), 0, stream,
                       part, lpart, bias, gamma, beta, mmean, mvar,
                       lossb, out);
    hipLaunchKernelGGL(loss_kernel, dim3(1), dim3(256), 0, stream,
                       lossb, out);
}

// Round 4
// 188.964 us; speedup vs baseline: 1.6171x; 1.6171x over previous
//
#include <hip/hip_runtime.h>

// GraphAttention fused forward for MI355X (gfx950).
// v4b: wave=head (lean regs, no spill) + double-buffered global_load_lds
// staging (1 barrier/stage, latency hidden) + XOR-swizzled LDS (conflict-free
// ds_read_b128) + exp2 fast path (s,t pre-scaled by log2e in prep; mask folded
// via fma; exp2 via guarded builtin/ocml-native) + JCA=4 (grid 1024 =
// 4 blocks/CU, part halved to 16.8MB).
// B=4, N=2048, F=64, FP=32, H=4.  Output: [B,N,H*FP] f32 ++ uloss ++ eloss.

#define B_ 4
#define N_ 2048
#define F_ 64
#define FP_ 32
#define H_ 4
#define C_ 128
#define IT_ 32                 // i-rows per attn block (2 per lane)
#define ITILES_ (N_ / IT_)     // 64
#define JCA_ 4                 // j-chunks -> grid 1024 (4 blocks/CU)
#define JSPANA_ (N_ / JCA_)    // 512
#define JST_ 64                // j per LDS stage
#define NST_ (JSPANA_ / JST_)  // 8 stages
#define LOG2E_ 1.44269504088896f

typedef __attribute__((ext_vector_type(8))) short short8v;   // 8 bf16 = 4 VGPRs
typedef __attribute__((ext_vector_type(4))) float f32x4;     // MFMA C/D
typedef __attribute__((ext_vector_type(4))) int   int4v;

union PkU { int4v i; short8v s; };

extern "C" __device__ float __ocml_native_exp2_f32(float);   // v_exp_f32 path

__device__ __forceinline__ float exp2fast(float x) {
#if __has_builtin(__builtin_amdgcn_exp2f)
    return __builtin_amdgcn_exp2f(x);
#else
    return __ocml_native_exp2_f32(x);
#endif
}

__device__ __forceinline__ unsigned short f2bf(float f) {    // RNE fp32->bf16
    unsigned u = __float_as_uint(f);
    u += 0x7fffu + ((u >> 16) & 1u);
    return (unsigned short)(u >> 16);
}

// 8 elementwise attn values -> l,A accumulate + packed bf16 A-frag dword x4.
// si,tv arrive PRE-SCALED by log2e; mask folded by fma; exp2 = v_exp_f32.
__device__ __forceinline__ void attn_qstep(
    float si, const float* av, const float* mv, const float* tv,
    float& l, float& A, int4v& apk)
{
#pragma unroll
    for (int qq = 0; qq < 4; ++qq) {
        float d0 = si + tv[2 * qq];
        d0 = fmaxf(d0, 0.2f * d0);                     // LeakyReLU (scaled dom)
        d0 = fmaf(mv[2 * qq], LOG2E_, d0);             // + mask*log2e
        float e0 = exp2fast(d0);
        float p0 = e0 * av[2 * qq];
        float d1 = si + tv[2 * qq + 1];
        d1 = fmaxf(d1, 0.2f * d1);
        d1 = fmaf(mv[2 * qq + 1], LOG2E_, d1);
        float e1 = exp2fast(d1);
        float p1 = e1 * av[2 * qq + 1];
        l += e0 + e1;
        A += p0 + p1;
        unsigned u0 = __float_as_uint(p0) + 0x8000u;   // round-half-up, p>=0
        unsigned u1 = __float_as_uint(p1) + 0x8000u;
        apk[qq] = (int)__builtin_amdgcn_perm(u1, u0, 0x07060302u); // [p1|p0]
    }
}

// async global->LDS, 16 B per lane; LDS dest wave-uniform base + lane*16.
__device__ __forceinline__ void gl_lds16(const float* g, float* l) {
    __builtin_amdgcn_global_load_lds(
        (const __attribute__((address_space(1))) unsigned*)g,
        (__attribute__((address_space(3))) unsigned*)l, 16, 0, 0);
}

// ---------------------------------------------------------------- kernel 1
// feats = x@W per head via MFMA; writes featsT bf16 [b][h][d][n] + s,t fp32
// (s,t pre-scaled by log2e for the attn exp2 path). Grid B*64 (full GPU).
__global__ __launch_bounds__(256) void prep_kernel(
    const float* __restrict__ x, const float* __restrict__ W,
    const float* __restrict__ a_self, const float* __restrict__ a_neigh,
    unsigned short* __restrict__ featsT, float* __restrict__ sbuf,
    float* __restrict__ tbuf)
{
    int blk = blockIdx.x;              // b*64 + nt
    int b = blk >> 6, nt = blk & 63;
    int n0 = nt << 5;
    int t = threadIdx.x, h = t >> 6, lane = t & 63;
    int quad = lane >> 4, col = lane & 15;

    short8v bw[2][2];
    const float* Wh = W + (size_t)h * F_ * FP_;
#pragma unroll
    for (int kc = 0; kc < 2; ++kc)
#pragma unroll
        for (int dt = 0; dt < 2; ++dt)
#pragma unroll
            for (int e = 0; e < 8; ++e) {
                int f = kc * 32 + quad * 8 + e;
                bw[kc][dt][e] = (short)f2bf(Wh[f * FP_ + dt * 16 + col]);
            }
    float as0 = a_self[h * FP_ + col],  as1 = a_self[h * FP_ + 16 + col];
    float an0 = a_neigh[h * FP_ + col], an1 = a_neigh[h * FP_ + 16 + col];
    size_t hrow = ((size_t)b * H_ + h) * N_;
    size_t ftb  = ((size_t)b * H_ + h) * FP_;

    for (int ms = 0; ms < 2; ++ms) {
        int row = n0 + ms * 16 + col;          // A row m = lane&15
        const float* xr = x + ((size_t)b * N_ + row) * F_;
        f32x4 acc0 = {0.f, 0.f, 0.f, 0.f}, acc1 = {0.f, 0.f, 0.f, 0.f};
#pragma unroll
        for (int kc = 0; kc < 2; ++kc) {
            float4 x0 = *(const float4*)(xr + kc * 32 + quad * 8);
            float4 x1 = *(const float4*)(xr + kc * 32 + quad * 8 + 4);
            short8v av;
            av[0] = (short)f2bf(x0.x); av[1] = (short)f2bf(x0.y);
            av[2] = (short)f2bf(x0.z); av[3] = (short)f2bf(x0.w);
            av[4] = (short)f2bf(x1.x); av[5] = (short)f2bf(x1.y);
            av[6] = (short)f2bf(x1.z); av[7] = (short)f2bf(x1.w);
            acc0 = __builtin_amdgcn_mfma_f32_16x16x32_bf16(av, bw[kc][0], acc0, 0, 0, 0);
            acc1 = __builtin_amdgcn_mfma_f32_16x16x32_bf16(av, bw[kc][1], acc1, 0, 0, 0);
        }
        {   // C layout: row = quad*4+rr, col = lane&15 (verified m89/m91)
            ushort4 v0, v1;
            v0.x = f2bf(acc0[0]); v0.y = f2bf(acc0[1]);
            v0.z = f2bf(acc0[2]); v0.w = f2bf(acc0[3]);
            v1.x = f2bf(acc1[0]); v1.y = f2bf(acc1[1]);
            v1.z = f2bf(acc1[2]); v1.w = f2bf(acc1[3]);
            size_t nidx = (size_t)n0 + ms * 16 + quad * 4;
            *(ushort4*)(featsT + (ftb + col) * N_ + nidx)      = v0;
            *(ushort4*)(featsT + (ftb + 16 + col) * N_ + nidx) = v1;
        }
#pragma unroll
        for (int rr = 0; rr < 4; ++rr) {
            float sv = acc0[rr] * as0 + acc1[rr] * as1;
            float tv = acc0[rr] * an0 + acc1[rr] * an1;
#pragma unroll
            for (int off = 8; off; off >>= 1) {
                sv += __shfl_down(sv, off);
                tv += __shfl_down(tv, off);
            }
            if (col == 0) {
                int n = n0 + ms * 16 + quad * 4 + rr;
                sbuf[hrow + n] = sv * LOG2E_;   // pre-scale for exp2 path
                tbuf[hrow + n] = tv * LOG2E_;
            }
        }
    }
}

// ---------------------------------------------------------------- kernel 2
// Block = (b, 32-row i-tile, jc). 4 waves = 4 heads. Double-buffered
// global_load_lds staging: issue stage(st+1), compute stage(st), one barrier.
// XOR swizzle: LDS row R stores col-group g^(R&7) at slot g (source
// pre-swizzled; read applies same XOR) -> conflict-free ds_read_b128.
__global__ __launch_bounds__(256, 4) void attn_kernel(
    const float* __restrict__ adj, const float* __restrict__ msk,
    const unsigned short* __restrict__ featsT,
    const float* __restrict__ sbuf, const float* __restrict__ tbuf,
    float* __restrict__ part, float* __restrict__ lpart)
{
    __shared__ __align__(16) float ladj[2][IT_ * JST_];   // 2 x 8 KB
    __shared__ __align__(16) float lmsk[2][IT_ * JST_];   // 2 x 8 KB
    __shared__ __align__(16) float lt[2][H_ * JST_];      // 2 x 1 KB

    const int blk = blockIdx.x;
    const int jc = blk & (JCA_ - 1);
    const int it = (blk >> 2) & (ITILES_ - 1);
    const int b  = blk >> 8;
    const int t = threadIdx.x, h = t >> 6, lane = t & 63;
    const int quad = lane >> 4, r = lane & 15;
    const int i0 = it * IT_;
    const int jbase = jc * JSPANA_;

    size_t hrow = ((size_t)b * H_ + h) * N_;
    float si0 = sbuf[hrow + i0 + r];          // pre-scaled by log2e
    float si1 = sbuf[hrow + i0 + 16 + r];
    // B-frag: lane(quad,r) holds featsT[d=r][j = base + quad*8 + e]
    const unsigned short* ft0 = featsT + (((size_t)b * H_ + h) * FP_ + r) * N_
                                + jbase + quad * 8;
    const unsigned short* ft1 = ft0 + (size_t)16 * N_;

    // staging: wave h stages adj/msk rows 8h..8h+7; instr ii covers 4 rows.
    // lane: row = 8h+4ii+(lane>>4), slot g = lane&15; src col = (g^(row&7))*4
    const float* asrc[2];
    const float* msrc[2];
#pragma unroll
    for (int ii = 0; ii < 2; ++ii) {
        int row = 8 * h + 4 * ii + (lane >> 4);
        int cs = ((lane & 15) ^ (row & 7)) << 2;
        size_t go = ((size_t)b * N_ + i0 + row) * N_ + jbase + cs;
        asrc[ii] = adj + go;
        msrc[ii] = msk + go;
    }
    // t staging: wave 0 stages all 4 heads [4][64], linear (broadcast reads)
    const float* tsrc = tbuf + ((size_t)b * H_ + (lane >> 4)) * N_
                        + jbase + ((lane & 15) << 2);

    f32x4 acc00 = {0.f,0.f,0.f,0.f}, acc01 = {0.f,0.f,0.f,0.f};
    f32x4 acc10 = {0.f,0.f,0.f,0.f}, acc11 = {0.f,0.f,0.f,0.f};
    float l0 = 0.f, A0 = 0.f, l1 = 0.f, A1 = 0.f;

    auto STAGE = [&](int bf, int st) {
        const int j0 = st * JST_;
#pragma unroll
        for (int ii = 0; ii < 2; ++ii) {
            gl_lds16(asrc[ii] + j0, &ladj[bf][(8 * h + 4 * ii) * JST_]);
            gl_lds16(msrc[ii] + j0, &lmsk[bf][(8 * h + 4 * ii) * JST_]);
        }
        if (h == 0) gl_lds16(tsrc + j0, &lt[bf][0]);
    };

    STAGE(0, 0);
    __syncthreads();                           // buf0 ready

    for (int st = 0; st < NST_; ++st) {
        const int bf = st & 1;
        if (st + 1 < NST_) STAGE(bf ^ 1, st + 1);      // prefetch next stage
        const int jg = st * JST_;                      // featsT col base
#pragma unroll
        for (int kc = 0; kc < 2; ++kc) {
            const int jt = kc * 32 + quad * 8;         // col in stage
            const int g0 = (jt >> 2) ^ (r & 7);        // swizzled slots
            const int g1 = ((jt >> 2) + 1) ^ (r & 7);  // (r+16: same &7)
            const int s0 = g0 << 2, s1 = g1 << 2;
            float4 a0l = *(const float4*)&ladj[bf][r * JST_ + s0];
            float4 a0h = *(const float4*)&ladj[bf][r * JST_ + s1];
            float4 a1l = *(const float4*)&ladj[bf][(r + 16) * JST_ + s0];
            float4 a1h = *(const float4*)&ladj[bf][(r + 16) * JST_ + s1];
            float4 m0l = *(const float4*)&lmsk[bf][r * JST_ + s0];
            float4 m0h = *(const float4*)&lmsk[bf][r * JST_ + s1];
            float4 m1l = *(const float4*)&lmsk[bf][(r + 16) * JST_ + s0];
            float4 m1h = *(const float4*)&lmsk[bf][(r + 16) * JST_ + s1];
            float4 t0 = *(const float4*)&lt[bf][h * JST_ + jt];       // bcast
            float4 t1 = *(const float4*)&lt[bf][h * JST_ + jt + 4];
            float tv[8] = {t0.x, t0.y, t0.z, t0.w, t1.x, t1.y, t1.z, t1.w};
            short8v bv0 = *(const short8v*)(ft0 + jg + kc * 32);      // L2/L3
            short8v bv1 = *(const short8v*)(ft1 + jg + kc * 32);
            PkU ap0, ap1;
            {   // rows r
                float av[8] = {a0l.x,a0l.y,a0l.z,a0l.w,a0h.x,a0h.y,a0h.z,a0h.w};
                float mv[8] = {m0l.x,m0l.y,m0l.z,m0l.w,m0h.x,m0h.y,m0h.z,m0h.w};
                attn_qstep(si0, av, mv, tv, l0, A0, ap0.i);
            }
            {   // rows r+16
                float av[8] = {a1l.x,a1l.y,a1l.z,a1l.w,a1h.x,a1h.y,a1h.z,a1h.w};
                float mv[8] = {m1l.x,m1l.y,m1l.z,m1l.w,m1h.x,m1h.y,m1h.z,m1h.w};
                attn_qstep(si1, av, mv, tv, l1, A1, ap1.i);
            }
            acc00 = __builtin_amdgcn_mfma_f32_16x16x32_bf16(ap0.s, bv0, acc00, 0, 0, 0);
            acc01 = __builtin_amdgcn_mfma_f32_16x16x32_bf16(ap0.s, bv1, acc01, 0, 0, 0);
            acc10 = __builtin_amdgcn_mfma_f32_16x16x32_bf16(ap1.s, bv0, acc10, 0, 0, 0);
            acc11 = __builtin_amdgcn_mfma_f32_16x16x32_bf16(ap1.s, bv1, acc11, 0, 0, 0);
        }
        __syncthreads();       // my stage loads drained; all waves advanced
    }

    // fold 4 k-group lanes -> row totals in lanes 0-15
    l0 += __shfl_down(l0, 32); l0 += __shfl_down(l0, 16);
    l1 += __shfl_down(l1, 32); l1 += __shfl_down(l1, 16);
    A0 += __shfl_down(A0, 32); A0 += __shfl_down(A0, 16);
    A1 += __shfl_down(A1, 32); A1 += __shfl_down(A1, 16);

    size_t pb = (((size_t)(b * H_ + h) * ITILES_ + it) * JCA_ + jc) * 1024;
    *(f32x4*)&part[pb + lane * 4]       = acc00;   // raw C-frags, coalesced
    *(f32x4*)&part[pb + 256 + lane * 4] = acc01;
    *(f32x4*)&part[pb + 512 + lane * 4] = acc10;
    *(f32x4*)&part[pb + 768 + lane * 4] = acc11;
    if (lane < 16) {
        size_t lb = (((size_t)(b * H_ + h) * ITILES_ + it) * JCA_ + jc) * 64;
        lpart[lb + lane]      = l0;      // rows 0-15
        lpart[lb + 16 + lane] = l1;      // rows 16-31
        lpart[lb + 32 + lane] = A0;
        lpart[lb + 48 + lane] = A1;
    }
}

// ---------------------------------------------------------------- kernel 3
// Block = (b, 32-row i-tile). Merge jc partials, /l, bias, BN, ReLU,
// LDS transpose, coalesced out; per-(block,h) eloss partial.
__global__ __launch_bounds__(256) void final_kernel(
    const float* __restrict__ part, const float* __restrict__ lpart,
    const float* __restrict__ bias, const float* __restrict__ gamma,
    const float* __restrict__ beta, const float* __restrict__ mmean,
    const float* __restrict__ mvar, float* __restrict__ lossbuf,
    float* __restrict__ out)
{
    __shared__ float ldsl[H_ * IT_];
    __shared__ float ldso[IT_ * 132];
    int blk = blockIdx.x;              // b*64 + it
    int b = blk >> 6, it = blk & 63;
    int t = threadIdx.x, h = t >> 6, lane = t & 63;
    int quad = lane >> 4, col = lane & 15;

    size_t pb = (((size_t)(b * H_ + h) * ITILES_ + it) * JCA_) * 1024;
    f32x4 C[4];
#pragma unroll
    for (int k = 0; k < 4; ++k) C[k] = (f32x4){0.f, 0.f, 0.f, 0.f};
#pragma unroll
    for (int c = 0; c < JCA_; ++c)
#pragma unroll
        for (int k = 0; k < 4; ++k)
            C[k] += *(const f32x4*)&part[pb + c * 1024 + k * 256 + lane * 4];

    size_t lb = (((size_t)(b * H_ + h) * ITILES_ + it) * JCA_) * 64;
    if (lane < 32) {
        float lt = 0.f, At = 0.f;
#pragma unroll
        for (int c = 0; c < JCA_; ++c) {
            lt += lpart[lb + c * 64 + lane];
            At += lpart[lb + c * 64 + 32 + lane];
        }
        ldsl[h * IT_ + lane] = lt;
        float e = At / lt;
#pragma unroll
        for (int off = 16; off; off >>= 1) e += __shfl_down(e, off);
        if (lane == 0) lossbuf[blk * H_ + h] = e;
    }
    __syncthreads();
#pragma unroll
    for (int dt = 0; dt < 2; ++dt) {
        int c = h * FP_ + dt * 16 + col;
        float sc = rsqrtf(mvar[c] + 1e-3f) * gamma[c];
        float sh = beta[c] - mmean[c] * sc;
        float bi = bias[c];
#pragma unroll
        for (int rr = 0; rr < 2; ++rr) {
            f32x4 Cv = C[rr * 2 + dt];
#pragma unroll
            for (int rrr = 0; rrr < 4; ++rrr) {
                int row = rr * 16 + quad * 4 + rrr;
                float node = Cv[rrr] / ldsl[h * IT_ + row] + bi;
                float o = node * sc + sh;
                ldso[row * 132 + c] = o > 0.f ? o : 0.f;
            }
        }
    }
    __syncthreads();
#pragma unroll
    for (int ps = 0; ps < 4; ++ps) {
        int s = ps * 256 + t;
        int row = s >> 5, c4 = (s & 31) * 4;
        *(float4*)(out + ((size_t)b * N_ + it * IT_ + row) * C_ + c4) =
            *(const float4*)&ldso[row * 132 + c4];
    }
}

// ---------------------------------------------------------------- kernel 4
__global__ __launch_bounds__(256) void loss_kernel(
    const float* __restrict__ lossbuf, float* __restrict__ out)
{
    float e = 0.f;
    for (int idx = threadIdx.x; idx < B_ * ITILES_ * H_; idx += 256)
        e += lossbuf[idx];
    __shared__ float se[256];
    se[threadIdx.x] = e;
    __syncthreads();
    for (int o = 128; o; o >>= 1) {
        if (threadIdx.x < o) se[threadIdx.x] += se[threadIdx.x + o];
        __syncthreads();
    }
    if (threadIdx.x == 0) {
        out[(size_t)B_ * N_ * C_]     = 0.f;                 // uloss == 0 exactly
        out[(size_t)B_ * N_ * C_ + 1] = se[0] * (1.f / N_);  // eloss
    }
}

// ---------------------------------------------------------------- launch
extern "C" void kernel_launch(void* const* d_in, const int* in_sizes, int n_in,
                              void* d_out, int out_size, void* d_ws, size_t ws_size,
                              hipStream_t stream)
{
    const float* x         = (const float*)d_in[0];
    const float* adj       = (const float*)d_in[1];
    const float* attn_mask = (const float*)d_in[2];
    const float* W         = (const float*)d_in[3];
    const float* a_self    = (const float*)d_in[4];
    const float* a_neigh   = (const float*)d_in[5];
    const float* bias      = (const float*)d_in[6];
    const float* gamma     = (const float*)d_in[7];
    const float* beta      = (const float*)d_in[8];
    const float* mmean     = (const float*)d_in[9];
    const float* mvar      = (const float*)d_in[10];
    float* out = (float*)d_out;

    float* ws = (float*)d_ws;
    unsigned short* featsT = (unsigned short*)ws;                      // 1,048,576 u16
    float* sbuf  = ws + 524288;                                        //    32,768 f
    float* tbuf  = sbuf + (size_t)B_ * H_ * N_;                        //    32,768 f
    float* part  = tbuf + (size_t)B_ * H_ * N_;                        // 4,194,304 f
    float* lpart = part + (size_t)B_ * H_ * ITILES_ * JCA_ * 1024;     //   262,144 f
    float* lossb = lpart + (size_t)B_ * H_ * ITILES_ * JCA_ * 64;      //     1,024 f

    hipLaunchKernelGGL(prep_kernel, dim3(B_ * 64), dim3(256), 0, stream,
                       x, W, a_self, a_neigh, featsT, sbuf, tbuf);
    hipLaunchKernelGGL(attn_kernel, dim3(B_ * ITILES_ * JCA_), dim3(256), 0, stream,
                       adj, attn_mask, featsT, sbuf, tbuf, part, lpart);
    hipLaunchKernelGGL(final_kernel, dim3(B_ * ITILES_), dim3(256), 0, stream,
                       part, lpart, bias, gamma, beta, mmean, mvar,
                       lossb, out);
    hipLaunchKernelGGL(loss_kernel, dim3(1), dim3(256), 0, stream,
                       lossb, out);
}